// Round 5
// baseline (3924.583 us; speedup 1.0000x reference)
//
#include <hip/hip_runtime.h>
#include <math.h>

#define N_NODES 100000
#define N_EDGES 3200000
#define HALF_E  1600000   // divisible by 256
#define F_IN 128
#define HID 16
#define C_OUT 10
#define NB 391            // ceil(N_NODES/256)
#define NBKT 7            // coarse buckets: col>>14 -> 0..6
#define BCAP 266240       // staging capacity per bucket per half (mean 262144, ~8.7 sigma margin)
#define STAGE_ENTRIES (6 * BCAP + 28672)  // bucket6 small (1696 nodes)

typedef unsigned short u16;
typedef unsigned int u32;
typedef unsigned long long u64;

__device__ __forceinline__ float bf2f(u16 u) {
    return __uint_as_float(((u32)u) << 16);
}
__device__ __forceinline__ u16 f2bf(float f) {
    u32 x = __float_as_uint(f);
    u32 r = (x + 0x7fffu + ((x >> 16) & 1u)) >> 16;  // round-nearest-even
    return (u16)r;
}

// ---------------- zero counters ----------------
__global__ void k_zero(int* __restrict__ deg, int* __restrict__ cursor, int* __restrict__ ccur) {
    int i = blockIdx.x * blockDim.x + threadIdx.x;
    if (i < N_NODES) { deg[i] = 0; cursor[i] = 0; }
    if (blockIdx.x == 0 && threadIdx.x < 2 * NBKT) ccur[threadIdx.x] = 0;
}

// ---------------- in-degree count (int atomics) ----------------
__global__ void k_count(const int* __restrict__ col, int* __restrict__ deg) {
    int e = blockIdx.x * blockDim.x + threadIdx.x;
    if (e < N_EDGES) atomicAdd(&deg[col[e]], 1);
}

// ---------------- scan phase 1: per-block sums of deg ----------------
__global__ void k_bsum(const int* __restrict__ deg, int* __restrict__ bsum) {
    __shared__ int sm[256];
    int i = blockIdx.x * 256 + threadIdx.x;
    sm[threadIdx.x] = (i < N_NODES) ? deg[i] : 0;
    __syncthreads();
    for (int off = 128; off > 0; off >>= 1) {
        if (threadIdx.x < off) sm[threadIdx.x] += sm[threadIdx.x + off];
        __syncthreads();
    }
    if (threadIdx.x == 0) bsum[blockIdx.x] = sm[0];
}

// ---------------- scan phase 2: 1-block scan of NB=391 partials ----------------
__global__ void k_bscan(const int* __restrict__ bsum, int* __restrict__ bpre,
                        int* __restrict__ offs) {
    const int T = 512;
    __shared__ int part[T];
    int t = threadIdx.x;
    part[t] = (t < NB) ? bsum[t] : 0;
    __syncthreads();
    for (int off = 1; off < T; off <<= 1) {
        int v = part[t];
        int u = (t >= off) ? part[t - off] : 0;
        __syncthreads();
        part[t] = v + u;
        __syncthreads();
    }
    if (t < NB) bpre[t] = (t > 0) ? part[t - 1] : 0;
    if (t == T - 1) offs[N_NODES] = part[T - 1];  // = E
}

// ---------------- scan phase 3: per-block exclusive scan -> offs; dis ----------------
__global__ void k_offs(const int* __restrict__ deg, const int* __restrict__ bpre,
                       int* __restrict__ offs, float* __restrict__ dis) {
    __shared__ int sm[256];
    int i = blockIdx.x * 256 + threadIdx.x;
    int t = threadIdx.x;
    int d = (i < N_NODES) ? deg[i] : 0;
    sm[t] = d;
    __syncthreads();
    for (int off = 1; off < 256; off <<= 1) {
        int v = sm[t];
        int u = (t >= off) ? sm[t - off] : 0;
        __syncthreads();
        sm[t] = v + u;
        __syncthreads();
    }
    if (i < N_NODES) {
        int excl = sm[t] - d;  // exclusive prefix within block
        offs[i] = bpre[blockIdx.x] + excl;
        dis[i] = rsqrtf(1.0f + (float)d);
    }
}

// ---------------- phase A: coarse partition (wave-aggregated appends) ----------------
// staging entry: (c & 16383) << 17 | src   (14 + 17 = 31 bits)
__global__ void k_part(const int* __restrict__ row, const int* __restrict__ col,
                       int* __restrict__ ccur, u32* __restrict__ staging, int half) {
    int i = blockIdx.x * blockDim.x + threadIdx.x;   // grid is exactly HALF_E threads
    int e = half * HALF_E + i;
    int r = row[e], c = col[e];
    int b = c >> 14;
    u32 packed = ((u32)(c & 16383) << 17) | (u32)r;
    int lane = threadIdx.x & 63;
#pragma unroll
    for (int bb = 0; bb < NBKT; bb++) {
        u64 mask = __ballot(b == bb);       // convergent: executed by all lanes
        if (b == bb) {
            int cnt = __popcll(mask);
            int leader = __ffsll((long long)mask) - 1;
            int base = 0;
            if (lane == leader) base = atomicAdd(&ccur[half * NBKT + bb], cnt);
            base = __shfl(base, leader);
            int rank = __popcll(mask & ((1ull << lane) - 1ull));
            staging[bb * BCAP + base + rank] = packed;
        }
    }
}

// ---------------- phase B: fine placement within coarse buckets ----------------
// blockIdx&7 selects the bucket (XCD-affinity heuristic): bucket b's csr region
// is a contiguous ~2MB block, so its random 4B writes stay L2-resident.
__global__ void k_place(const u32* __restrict__ staging, const int* __restrict__ ccur,
                        const int* __restrict__ offs, int* __restrict__ cursor,
                        int* __restrict__ csr, int half) {
    int x = blockIdx.x & 7;
    int b = (x == 7) ? 6 : x;
    int J = gridDim.x >> 3;
    int j = (int)(blockIdx.x >> 3) + ((x == 7) ? J : 0);
    int nb = (b == 6) ? 2 * J : J;
    int cnt = ccur[half * NBKT + b];
    int base = b * BCAP;
    for (int i = j * 256 + (int)threadIdx.x; i < cnt; i += nb * 256) {
        u32 p = staging[base + i];
        int c = (b << 14) + (int)(p >> 17);
        int s = (int)(p & 0x1FFFFu);
        int pos = atomicAdd(&cursor[c], 1);
        csr[offs[c] + pos] = s;
    }
}

// ---------------- layer 1 GEMM: h1s = (x @ W1) * dis[node]  (bf16) ----------------
__global__ void k_gemm1(const float* __restrict__ x, const float* __restrict__ W1,
                        const float* __restrict__ dis, u16* __restrict__ h1s) {
    __shared__ float Ws[F_IN * HID];  // 8 KB
    for (int t = threadIdx.x; t < F_IN * HID; t += blockDim.x) Ws[t] = W1[t];
    __syncthreads();

    int node = blockIdx.x * blockDim.x + threadIdx.x;
    if (node >= N_NODES) return;

    float acc[HID];
#pragma unroll
    for (int j = 0; j < HID; j++) acc[j] = 0.f;

    const float4* xr = (const float4*)(x + (size_t)node * F_IN);
#pragma unroll 2
    for (int k4 = 0; k4 < F_IN / 4; k4++) {
        float4 v = xr[k4];
        float xv[4] = {v.x, v.y, v.z, v.w};
#pragma unroll
        for (int kk = 0; kk < 4; kk++) {
            const float4* wr = (const float4*)(Ws + (k4 * 4 + kk) * HID);
            float4 w0 = wr[0], w1 = wr[1], w2 = wr[2], w3 = wr[3];
            float xs = xv[kk];
            acc[0]  += xs * w0.x; acc[1]  += xs * w0.y; acc[2]  += xs * w0.z; acc[3]  += xs * w0.w;
            acc[4]  += xs * w1.x; acc[5]  += xs * w1.y; acc[6]  += xs * w1.z; acc[7]  += xs * w1.w;
            acc[8]  += xs * w2.x; acc[9]  += xs * w2.y; acc[10] += xs * w2.z; acc[11] += xs * w2.w;
            acc[12] += xs * w3.x; acc[13] += xs * w3.y; acc[14] += xs * w3.z; acc[15] += xs * w3.w;
        }
    }

    float d = dis[node];
    u32 p[8];
#pragma unroll
    for (int i = 0; i < 8; i++)
        p[i] = (u32)f2bf(acc[2 * i] * d) | ((u32)f2bf(acc[2 * i + 1] * d) << 16);
    u32* dst = (u32*)(h1s + (size_t)node * HID);
#pragma unroll
    for (int i = 0; i < 8; i++) dst[i] = p[i];
}

// ---------------- gather layer 1 ----------------
__global__ void k_gather1(const int* __restrict__ offs, const int* __restrict__ csr_src,
                          const float* __restrict__ dis, const u16* __restrict__ h1s,
                          u16* __restrict__ agg1) {
    long long t = (long long)blockIdx.x * blockDim.x + threadIdx.x;
    if (t >= (long long)N_NODES * 8) return;
    int node = (int)(t >> 3);
    int f2 = (int)(t & 7);
    const u32* base = (const u32*)h1s;
    u32 v = base[(size_t)node * 8 + f2];  // self loop (already * dis[node])
    float a0 = bf2f((u16)(v & 0xffff));
    float a1 = bf2f((u16)(v >> 16));
    int s0 = offs[node], s1 = offs[node + 1];
    for (int j = s0; j < s1; j++) {
        int s = csr_src[j];  // broadcast across the node's 8 lanes
        u32 w = base[(size_t)s * 8 + f2];
        a0 += bf2f((u16)(w & 0xffff));
        a1 += bf2f((u16)(w >> 16));
    }
    float dc = dis[node];
    ((u32*)agg1)[(size_t)node * 8 + f2] =
        (u32)f2bf(a0 * dc) | ((u32)f2bf(a1 * dc) << 16);
}

// ---------------- layer 2 ----------------
__global__ void k_layer2(const u16* __restrict__ agg1, const float* __restrict__ b1,
                         const float* __restrict__ W2, const float* __restrict__ dis,
                         u16* __restrict__ h2s) {
    __shared__ float Ws[HID * C_OUT];
    __shared__ float b1s[HID];
    if (threadIdx.x < HID * C_OUT) Ws[threadIdx.x] = W2[threadIdx.x];
    if (threadIdx.x < HID) b1s[threadIdx.x] = b1[threadIdx.x];
    __syncthreads();

    int node = blockIdx.x * blockDim.x + threadIdx.x;
    if (node >= N_NODES) return;

    const uint4* ar = (const uint4*)(agg1 + (size_t)node * HID);
    uint4 q0 = ar[0], q1 = ar[1];
    u32 qs[8] = {q0.x, q0.y, q0.z, q0.w, q1.x, q1.y, q1.z, q1.w};

    float acc[C_OUT];
#pragma unroll
    for (int k = 0; k < C_OUT; k++) acc[k] = 0.f;

#pragma unroll
    for (int i = 0; i < 8; i++) {
        u32 q = qs[i];
        float v0 = bf2f((u16)(q & 0xffff));
        float v1 = bf2f((u16)(q >> 16));
        int j0 = 2 * i, j1 = 2 * i + 1;
        float h0 = fmaxf(v0 + b1s[j0], 0.f);
        float h1v = fmaxf(v1 + b1s[j1], 0.f);
#pragma unroll
        for (int k = 0; k < C_OUT; k++) acc[k] += h0 * Ws[j0 * C_OUT + k] + h1v * Ws[j1 * C_OUT + k];
    }

    float d = dis[node];
    u32 p[8];
#pragma unroll
    for (int i = 0; i < 5; i++)
        p[i] = (u32)f2bf(acc[2 * i] * d) | ((u32)f2bf(acc[2 * i + 1] * d) << 16);
    p[5] = 0; p[6] = 0; p[7] = 0;  // pad features 10..15
    u32* dst = (u32*)(h2s + (size_t)node * HID);
#pragma unroll
    for (int i = 0; i < 8; i++) dst[i] = p[i];
}

// ---------------- gather layer 2 -> d_out (fp32) ----------------
__global__ void k_gather2(const int* __restrict__ offs, const int* __restrict__ csr_src,
                          const float* __restrict__ dis, const u16* __restrict__ h2s,
                          float* __restrict__ agg2) {
    long long t = (long long)blockIdx.x * blockDim.x + threadIdx.x;
    if (t >= (long long)N_NODES * 8) return;
    int node = (int)(t >> 3);
    int f2 = (int)(t & 7);
    const u32* base = (const u32*)h2s;
    u32 v = base[(size_t)node * 8 + f2];
    float a0 = bf2f((u16)(v & 0xffff));
    float a1 = bf2f((u16)(v >> 16));
    int s0 = offs[node], s1 = offs[node + 1];
    for (int j = s0; j < s1; j++) {
        int s = csr_src[j];
        u32 w = base[(size_t)s * 8 + f2];
        a0 += bf2f((u16)(w & 0xffff));
        a1 += bf2f((u16)(w >> 16));
    }
    if (f2 < 5) {
        float dc = dis[node];
        float2 o = make_float2(a0 * dc, a1 * dc);
        *(float2*)(agg2 + (size_t)node * C_OUT + 2 * f2) = o;
    }
}

// ---------------- final: log_softmax in place on d_out ----------------
__global__ void k_final(float* __restrict__ agg2, const float* __restrict__ b2) {
    __shared__ float b2s[C_OUT];
    if (threadIdx.x < C_OUT) b2s[threadIdx.x] = b2[threadIdx.x];
    __syncthreads();

    int i = blockIdx.x * blockDim.x + threadIdx.x;
    if (i >= N_NODES) return;

    float* ar = agg2 + (size_t)i * C_OUT;
    float v[C_OUT];
    float m = -1e30f;
#pragma unroll
    for (int k = 0; k < C_OUT; k++) {
        v[k] = ar[k] + b2s[k];
        m = fmaxf(m, v[k]);
    }
    float s = 0.f;
#pragma unroll
    for (int k = 0; k < C_OUT; k++) s += expf(v[k] - m);
    float ls = logf(s) + m;
#pragma unroll
    for (int k = 0; k < C_OUT; k++) ar[k] = v[k] - ls;
}

// ---------------- launch ----------------
extern "C" void kernel_launch(void* const* d_in, const int* in_sizes, int n_in,
                              void* d_out, int out_size, void* d_ws, size_t ws_size,
                              hipStream_t stream) {
    const float* x  = (const float*)d_in[0];
    const int*   ei = (const int*)d_in[1];
    const float* W1 = (const float*)d_in[2];
    const float* b1 = (const float*)d_in[3];
    const float* W2 = (const float*)d_in[4];
    const float* b2 = (const float*)d_in[5];
    float* out = (float*)d_out;

    const int* row = ei;            // sources
    const int* col = ei + N_EDGES;  // targets

    // workspace layout (~20.9 MB; staging aliases h1s+agg1 — disjoint lifetimes)
    char* ws = (char*)d_ws;
    float* dis    = (float*)(ws);                     // [0, 400000)
    int*   offs   = (int*)(ws + 400000);              // [400000, 800016)   N+1
    int*   deg    = (int*)(ws + 800016);              // [800016, 1200016)
    int*   cursor = (int*)(ws + 1200016);             // [1200016, 1600016)
    int*   bsum   = (int*)(ws + 1600016);             // 1568 B
    int*   bpre   = (int*)(ws + 1601584);             // 1568 B
    int*   ccur   = (int*)(ws + 1603152);             // 14 ints (2 halves x 7 buckets)
    int*   csr    = (int*)(ws + 1603216);             // 12.8 MB
    u32*   staging= (u32*)(ws + 14403216);            // 6504448 B  [dead after k_place]
    u16*   h1s    = (u16*)(ws + 14403216);            // 3.2 MB (alias staging)
    u16*   h2s    = (u16*)(ws + 14403216);            // alias (padded to 16)
    u16*   agg1   = (u16*)(ws + 17603216);            // 3.2 MB (alias staging tail)
    float* agg2   = out;                              // d_out, finalized in place

    const int B = 256;
    int gN  = (N_NODES + B - 1) / B;   // 391
    int gE  = (N_EDGES + B - 1) / B;
    int gH  = HALF_E / B;              // 6250, exact
    int gN8 = (int)(((long long)N_NODES * 8 + B - 1) / B);

    k_zero   <<<gN, B, 0, stream>>>(deg, cursor, ccur);
    k_count  <<<gE, B, 0, stream>>>(col, deg);
    k_bsum   <<<NB, B, 0, stream>>>(deg, bsum);
    k_bscan  <<<1, 512, 0, stream>>>(bsum, bpre, offs);
    k_offs   <<<NB, B, 0, stream>>>(deg, bpre, offs, dis);
    k_part   <<<gH, B, 0, stream>>>(row, col, ccur, staging, 0);
    k_place  <<<2048, B, 0, stream>>>(staging, ccur, offs, cursor, csr, 0);
    k_part   <<<gH, B, 0, stream>>>(row, col, ccur, staging, 1);
    k_place  <<<2048, B, 0, stream>>>(staging, ccur, offs, cursor, csr, 1);
    k_gemm1  <<<gN, B, 0, stream>>>(x, W1, dis, h1s);
    k_gather1<<<gN8, B, 0, stream>>>(offs, csr, dis, h1s, agg1);
    k_layer2 <<<gN, B, 0, stream>>>(agg1, b1, W2, dis, h2s);
    k_gather2<<<gN8, B, 0, stream>>>(offs, csr, dis, h2s, agg2);
    k_final  <<<gN, B, 0, stream>>>(agg2, b2);
}

// Round 6
// 528.062 us; speedup vs baseline: 7.4320x; 7.4320x over previous
//
#include <hip/hip_runtime.h>
#include <math.h>

#define N_NODES 100000
#define N_EDGES 3200000
#define HALF_E  1600000   // divisible by 256
#define F_IN 128
#define HID 16
#define C_OUT 10
#define NB 391            // ceil(N_NODES/256)
#define NBKT 7            // coarse buckets: col>>14 -> 0..6
#define PNB 1024          // partition blocks per half
#define CH 1563           // ceil(HALF_E / PNB)

typedef unsigned short u16;
typedef unsigned int u32;
typedef unsigned long long u64;

__device__ __forceinline__ float bf2f(u16 u) {
    return __uint_as_float(((u32)u) << 16);
}
__device__ __forceinline__ u16 f2bf(float f) {
    u32 x = __float_as_uint(f);
    u32 r = (x + 0x7fffu + ((x >> 16) & 1u)) >> 16;  // round-nearest-even
    return (u16)r;
}

// ---------------- zero counters ----------------
__global__ void k_zero(int* __restrict__ deg, int* __restrict__ cursor) {
    int i = blockIdx.x * blockDim.x + threadIdx.x;
    if (i < N_NODES) { deg[i] = 0; cursor[i] = 0; }
}

// ---------------- in-degree count (int atomics, 100K distinct counters) ----------------
__global__ void k_count(const int* __restrict__ col, int* __restrict__ deg) {
    int e = blockIdx.x * blockDim.x + threadIdx.x;
    if (e < N_EDGES) atomicAdd(&deg[col[e]], 1);
}

// ---------------- scan phase 1: per-block sums of deg ----------------
__global__ void k_bsum(const int* __restrict__ deg, int* __restrict__ bsum) {
    __shared__ int sm[256];
    int i = blockIdx.x * 256 + threadIdx.x;
    sm[threadIdx.x] = (i < N_NODES) ? deg[i] : 0;
    __syncthreads();
    for (int off = 128; off > 0; off >>= 1) {
        if (threadIdx.x < off) sm[threadIdx.x] += sm[threadIdx.x + off];
        __syncthreads();
    }
    if (threadIdx.x == 0) bsum[blockIdx.x] = sm[0];
}

// ---------------- scan phase 2: 1-block scan of NB=391 partials ----------------
__global__ void k_bscan(const int* __restrict__ bsum, int* __restrict__ bpre,
                        int* __restrict__ offs) {
    const int T = 512;
    __shared__ int part[T];
    int t = threadIdx.x;
    part[t] = (t < NB) ? bsum[t] : 0;
    __syncthreads();
    for (int off = 1; off < T; off <<= 1) {
        int v = part[t];
        int u = (t >= off) ? part[t - off] : 0;
        __syncthreads();
        part[t] = v + u;
        __syncthreads();
    }
    if (t < NB) bpre[t] = (t > 0) ? part[t - 1] : 0;
    if (t == T - 1) offs[N_NODES] = part[T - 1];  // = E
}

// ---------------- scan phase 3: per-block exclusive scan -> offs; dis ----------------
__global__ void k_offs(const int* __restrict__ deg, const int* __restrict__ bpre,
                       int* __restrict__ offs, float* __restrict__ dis) {
    __shared__ int sm[256];
    int i = blockIdx.x * 256 + threadIdx.x;
    int t = threadIdx.x;
    int d = (i < N_NODES) ? deg[i] : 0;
    sm[t] = d;
    __syncthreads();
    for (int off = 1; off < 256; off <<= 1) {
        int v = sm[t];
        int u = (t >= off) ? sm[t - off] : 0;
        __syncthreads();
        sm[t] = v + u;
        __syncthreads();
    }
    if (i < N_NODES) {
        int excl = sm[t] - d;  // exclusive prefix within block
        offs[i] = bpre[blockIdx.x] + excl;
        dis[i] = rsqrtf(1.0f + (float)d);
    }
}

// ---------------- partition A1: per-block LDS histogram of coarse buckets ----------------
__global__ void k_pcnt(const int* __restrict__ col, int* __restrict__ blkhist, int half) {
    __shared__ int h[NBKT];
    if (threadIdx.x < NBKT) h[threadIdx.x] = 0;
    __syncthreads();
    int lo = blockIdx.x * CH;
    int hi = lo + CH; if (hi > HALF_E) hi = HALF_E;
    for (int i = lo + threadIdx.x; i < hi; i += 256) {
        int c = col[half * HALF_E + i];
        atomicAdd(&h[c >> 14], 1);  // LDS atomic
    }
    __syncthreads();
    if (threadIdx.x < NBKT)
        blkhist[threadIdx.x * PNB + blockIdx.x] = h[threadIdx.x];  // bucket-major
}

// ---------------- partition A2: exclusive scan of 7168 block-histogram entries ----------------
__global__ void k_pscan(const int* __restrict__ blkhist, int* __restrict__ sbase) {
    const int T = 1024, PER = NBKT;  // 1024 * 7 = 7168
    __shared__ int part[T];
    int t = threadIdx.x;
    int vals[PER];
    int s = 0;
#pragma unroll
    for (int j = 0; j < PER; j++) { vals[j] = blkhist[t * PER + j]; s += vals[j]; }
    part[t] = s;
    __syncthreads();
    for (int off = 1; off < T; off <<= 1) {
        int v = part[t];
        int u = (t >= off) ? part[t - off] : 0;
        __syncthreads();
        part[t] = v + u;
        __syncthreads();
    }
    int run = (t > 0) ? part[t - 1] : 0;
#pragma unroll
    for (int j = 0; j < PER; j++) { sbase[t * PER + j] = run; run += vals[j]; }
    if (t == T - 1) sbase[NBKT * PNB] = run;  // = HALF_E
}

// ---------------- partition A3: write staging at deterministic offsets ----------------
// staging entry: (c & 16383) << 17 | src   (14 + 17 = 31 bits)
__global__ void k_pwrite(const int* __restrict__ row, const int* __restrict__ col,
                         const int* __restrict__ sbase, u32* __restrict__ staging, int half) {
    __shared__ int base[NBKT];
    __shared__ int lcur[NBKT];
    if (threadIdx.x < NBKT) {
        base[threadIdx.x] = sbase[threadIdx.x * PNB + blockIdx.x];
        lcur[threadIdx.x] = 0;
    }
    __syncthreads();
    int lo = blockIdx.x * CH;
    int hi = lo + CH; if (hi > HALF_E) hi = HALF_E;
    for (int i = lo + threadIdx.x; i < hi; i += 256) {
        int e = half * HALF_E + i;
        int c = col[e];
        int b = c >> 14;
        int rank = atomicAdd(&lcur[b], 1);  // LDS atomic
        staging[base[b] + rank] = ((u32)(c & 16383) << 17) | (u32)row[e];
    }
}

// ---------------- phase B: fine placement within coarse buckets ----------------
// blockIdx&7 -> bucket (XCD-affinity heuristic); bucket b's csr region is a
// contiguous ~2MB block so its random 4B writes stay L2-resident.
__global__ void k_place(const u32* __restrict__ staging, const int* __restrict__ sbase,
                        const int* __restrict__ offs, int* __restrict__ cursor,
                        int* __restrict__ csr) {
    int x = blockIdx.x & 7;
    int b = (x == 7) ? 6 : x;
    int J = gridDim.x >> 3;
    int j = (int)(blockIdx.x >> 3) + ((x == 7) ? J : 0);
    int nb = (b == 6) ? 2 * J : J;
    int start = sbase[b * PNB];
    int end = (b == NBKT - 1) ? HALF_E : sbase[(b + 1) * PNB];
    for (int i = start + j * 256 + (int)threadIdx.x; i < end; i += nb * 256) {
        u32 p = staging[i];
        int c = (b << 14) + (int)(p >> 17);
        int s = (int)(p & 0x1FFFFu);
        int pos = atomicAdd(&cursor[c], 1);
        csr[offs[c] + pos] = s;
    }
}

// ---------------- layer 1 GEMM: h1s = (x @ W1) * dis[node]  (bf16) ----------------
__global__ void k_gemm1(const float* __restrict__ x, const float* __restrict__ W1,
                        const float* __restrict__ dis, u16* __restrict__ h1s) {
    __shared__ float Ws[F_IN * HID];  // 8 KB
    for (int t = threadIdx.x; t < F_IN * HID; t += blockDim.x) Ws[t] = W1[t];
    __syncthreads();

    int node = blockIdx.x * blockDim.x + threadIdx.x;
    if (node >= N_NODES) return;

    float acc[HID];
#pragma unroll
    for (int j = 0; j < HID; j++) acc[j] = 0.f;

    const float4* xr = (const float4*)(x + (size_t)node * F_IN);
#pragma unroll 2
    for (int k4 = 0; k4 < F_IN / 4; k4++) {
        float4 v = xr[k4];
        float xv[4] = {v.x, v.y, v.z, v.w};
#pragma unroll
        for (int kk = 0; kk < 4; kk++) {
            const float4* wr = (const float4*)(Ws + (k4 * 4 + kk) * HID);
            float4 w0 = wr[0], w1 = wr[1], w2 = wr[2], w3 = wr[3];
            float xs = xv[kk];
            acc[0]  += xs * w0.x; acc[1]  += xs * w0.y; acc[2]  += xs * w0.z; acc[3]  += xs * w0.w;
            acc[4]  += xs * w1.x; acc[5]  += xs * w1.y; acc[6]  += xs * w1.z; acc[7]  += xs * w1.w;
            acc[8]  += xs * w2.x; acc[9]  += xs * w2.y; acc[10] += xs * w2.z; acc[11] += xs * w2.w;
            acc[12] += xs * w3.x; acc[13] += xs * w3.y; acc[14] += xs * w3.z; acc[15] += xs * w3.w;
        }
    }

    float d = dis[node];
    u32 p[8];
#pragma unroll
    for (int i = 0; i < 8; i++)
        p[i] = (u32)f2bf(acc[2 * i] * d) | ((u32)f2bf(acc[2 * i + 1] * d) << 16);
    u32* dst = (u32*)(h1s + (size_t)node * HID);
#pragma unroll
    for (int i = 0; i < 8; i++) dst[i] = p[i];
}

// ---------------- gather layer 1 ----------------
__global__ void k_gather1(const int* __restrict__ offs, const int* __restrict__ csr_src,
                          const float* __restrict__ dis, const u16* __restrict__ h1s,
                          u16* __restrict__ agg1) {
    long long t = (long long)blockIdx.x * blockDim.x + threadIdx.x;
    if (t >= (long long)N_NODES * 8) return;
    int node = (int)(t >> 3);
    int f2 = (int)(t & 7);
    const u32* base = (const u32*)h1s;
    u32 v = base[(size_t)node * 8 + f2];  // self loop (already * dis[node])
    float a0 = bf2f((u16)(v & 0xffff));
    float a1 = bf2f((u16)(v >> 16));
    int s0 = offs[node], s1 = offs[node + 1];
    for (int j = s0; j < s1; j++) {
        int s = csr_src[j];  // broadcast across the node's 8 lanes
        u32 w = base[(size_t)s * 8 + f2];
        a0 += bf2f((u16)(w & 0xffff));
        a1 += bf2f((u16)(w >> 16));
    }
    float dc = dis[node];
    ((u32*)agg1)[(size_t)node * 8 + f2] =
        (u32)f2bf(a0 * dc) | ((u32)f2bf(a1 * dc) << 16);
}

// ---------------- layer 2 ----------------
__global__ void k_layer2(const u16* __restrict__ agg1, const float* __restrict__ b1,
                         const float* __restrict__ W2, const float* __restrict__ dis,
                         u16* __restrict__ h2s) {
    __shared__ float Ws[HID * C_OUT];
    __shared__ float b1s[HID];
    if (threadIdx.x < HID * C_OUT) Ws[threadIdx.x] = W2[threadIdx.x];
    if (threadIdx.x < HID) b1s[threadIdx.x] = b1[threadIdx.x];
    __syncthreads();

    int node = blockIdx.x * blockDim.x + threadIdx.x;
    if (node >= N_NODES) return;

    const uint4* ar = (const uint4*)(agg1 + (size_t)node * HID);
    uint4 q0 = ar[0], q1 = ar[1];
    u32 qs[8] = {q0.x, q0.y, q0.z, q0.w, q1.x, q1.y, q1.z, q1.w};

    float acc[C_OUT];
#pragma unroll
    for (int k = 0; k < C_OUT; k++) acc[k] = 0.f;

#pragma unroll
    for (int i = 0; i < 8; i++) {
        u32 q = qs[i];
        float v0 = bf2f((u16)(q & 0xffff));
        float v1 = bf2f((u16)(q >> 16));
        int j0 = 2 * i, j1 = 2 * i + 1;
        float h0 = fmaxf(v0 + b1s[j0], 0.f);
        float h1v = fmaxf(v1 + b1s[j1], 0.f);
#pragma unroll
        for (int k = 0; k < C_OUT; k++) acc[k] += h0 * Ws[j0 * C_OUT + k] + h1v * Ws[j1 * C_OUT + k];
    }

    float d = dis[node];
    u32 p[8];
#pragma unroll
    for (int i = 0; i < 5; i++)
        p[i] = (u32)f2bf(acc[2 * i] * d) | ((u32)f2bf(acc[2 * i + 1] * d) << 16);
    p[5] = 0; p[6] = 0; p[7] = 0;  // pad features 10..15
    u32* dst = (u32*)(h2s + (size_t)node * HID);
#pragma unroll
    for (int i = 0; i < 8; i++) dst[i] = p[i];
}

// ---------------- gather layer 2 -> d_out (fp32) ----------------
__global__ void k_gather2(const int* __restrict__ offs, const int* __restrict__ csr_src,
                          const float* __restrict__ dis, const u16* __restrict__ h2s,
                          float* __restrict__ agg2) {
    long long t = (long long)blockIdx.x * blockDim.x + threadIdx.x;
    if (t >= (long long)N_NODES * 8) return;
    int node = (int)(t >> 3);
    int f2 = (int)(t & 7);
    const u32* base = (const u32*)h2s;
    u32 v = base[(size_t)node * 8 + f2];
    float a0 = bf2f((u16)(v & 0xffff));
    float a1 = bf2f((u16)(v >> 16));
    int s0 = offs[node], s1 = offs[node + 1];
    for (int j = s0; j < s1; j++) {
        int s = csr_src[j];
        u32 w = base[(size_t)s * 8 + f2];
        a0 += bf2f((u16)(w & 0xffff));
        a1 += bf2f((u16)(w >> 16));
    }
    if (f2 < 5) {
        float dc = dis[node];
        float2 o = make_float2(a0 * dc, a1 * dc);
        *(float2*)(agg2 + (size_t)node * C_OUT + 2 * f2) = o;
    }
}

// ---------------- final: log_softmax in place on d_out ----------------
__global__ void k_final(float* __restrict__ agg2, const float* __restrict__ b2) {
    __shared__ float b2s[C_OUT];
    if (threadIdx.x < C_OUT) b2s[threadIdx.x] = b2[threadIdx.x];
    __syncthreads();

    int i = blockIdx.x * blockDim.x + threadIdx.x;
    if (i >= N_NODES) return;

    float* ar = agg2 + (size_t)i * C_OUT;
    float v[C_OUT];
    float m = -1e30f;
#pragma unroll
    for (int k = 0; k < C_OUT; k++) {
        v[k] = ar[k] + b2s[k];
        m = fmaxf(m, v[k]);
    }
    float s = 0.f;
#pragma unroll
    for (int k = 0; k < C_OUT; k++) s += expf(v[k] - m);
    float ls = logf(s) + m;
#pragma unroll
    for (int k = 0; k < C_OUT; k++) ar[k] = v[k] - ls;
}

// ---------------- launch ----------------
extern "C" void kernel_launch(void* const* d_in, const int* in_sizes, int n_in,
                              void* d_out, int out_size, void* d_ws, size_t ws_size,
                              hipStream_t stream) {
    const float* x  = (const float*)d_in[0];
    const int*   ei = (const int*)d_in[1];
    const float* W1 = (const float*)d_in[2];
    const float* b1 = (const float*)d_in[3];
    const float* W2 = (const float*)d_in[4];
    const float* b2 = (const float*)d_in[5];
    float* out = (float*)d_out;

    const int* row = ei;            // sources
    const int* col = ei + N_EDGES;  // targets

    // workspace layout (~20.9 MB; staging aliases h1s+agg1 — disjoint lifetimes)
    char* ws = (char*)d_ws;
    float* dis    = (float*)(ws);                     // [0, 400000)
    int*   offs   = (int*)(ws + 400000);              // N+1 ints
    int*   deg    = (int*)(ws + 800016);
    int*   cursor = (int*)(ws + 1200016);
    int*   bsum   = (int*)(ws + 1600016);             // 1568 B
    int*   bpre   = (int*)(ws + 1601584);             // 1568 B
    int*   blkhist= (int*)(ws + 1603152);             // 7168 ints = 28672 B
    int*   sbase  = (int*)(ws + 1631824);             // 7169 ints = 28676 B
    int*   csr    = (int*)(ws + 1660512);             // 12.8 MB
    u32*   staging= (u32*)(ws + 14460512);            // 6.4 MB  [dead after k_place]
    u16*   h1s    = (u16*)(ws + 14460512);            // 3.2 MB (alias staging)
    u16*   h2s    = (u16*)(ws + 14460512);            // alias (padded to 16)
    u16*   agg1   = (u16*)(ws + 17660512);            // 3.2 MB (alias staging tail)
    float* agg2   = out;                              // d_out, finalized in place

    const int B = 256;
    int gN  = (N_NODES + B - 1) / B;   // 391
    int gE  = (N_EDGES + B - 1) / B;
    int gN8 = (int)(((long long)N_NODES * 8 + B - 1) / B);

    k_zero   <<<gN, B, 0, stream>>>(deg, cursor);
    k_count  <<<gE, B, 0, stream>>>(col, deg);
    k_bsum   <<<NB, B, 0, stream>>>(deg, bsum);
    k_bscan  <<<1, 512, 0, stream>>>(bsum, bpre, offs);
    k_offs   <<<NB, B, 0, stream>>>(deg, bpre, offs, dis);
    // half 0 partition + place
    k_pcnt   <<<PNB, B, 0, stream>>>(col, blkhist, 0);
    k_pscan  <<<1, 1024, 0, stream>>>(blkhist, sbase);
    k_pwrite <<<PNB, B, 0, stream>>>(row, col, sbase, staging, 0);
    k_place  <<<2048, B, 0, stream>>>(staging, sbase, offs, cursor, csr);
    // half 1 partition + place
    k_pcnt   <<<PNB, B, 0, stream>>>(col, blkhist, 1);
    k_pscan  <<<1, 1024, 0, stream>>>(blkhist, sbase);
    k_pwrite <<<PNB, B, 0, stream>>>(row, col, sbase, staging, 1);
    k_place  <<<2048, B, 0, stream>>>(staging, sbase, offs, cursor, csr);
    // dense pipeline
    k_gemm1  <<<gN, B, 0, stream>>>(x, W1, dis, h1s);
    k_gather1<<<gN8, B, 0, stream>>>(offs, csr, dis, h1s, agg1);
    k_layer2 <<<gN, B, 0, stream>>>(agg1, b1, W2, dis, h2s);
    k_gather2<<<gN8, B, 0, stream>>>(offs, csr, dis, h2s, agg2);
    k_final  <<<gN, B, 0, stream>>>(agg2, b2);
}